// Round 7
// baseline (363.985 us; speedup 1.0000x reference)
//
#include <hip/hip_runtime.h>
#include <hip/hip_bf16.h>
#include <hip/hip_fp16.h>
#include <cstddef>

#define B_  8
#define N_  8192
#define C_  256
#define H_  128
#define W_  128
#define HH  8
#define PP  4
#define DD  32
#define HW  (H_ * W_)

typedef short bf16x8 __attribute__((ext_vector_type(8)));
typedef _Float16 f16x8 __attribute__((ext_vector_type(8)));
typedef float f32x4  __attribute__((ext_vector_type(4)));

static __device__ __forceinline__ short f2bf_s(float f) {
    __hip_bfloat16 b = __float2bfloat16(f);
    return *reinterpret_cast<short*>(&b);
}
static __device__ __forceinline__ float bf_s2f(short s) {
    __hip_bfloat16 b = *reinterpret_cast<__hip_bfloat16*>(&s);
    return __bfloat162float(b);
}

// ---------------------------------------------------------------------------
// kTP: merged prep kernel.
//  blocks [0, 4096):    transpose value (B,256,H,W) f32 -> val (B*8, HW, 32) f16
//    v3: stride-260 tile (16B-aligned -> ds_write_b128, conflict-free) +
//        XOR swizzle slot^=(d>>3)<<2 so read phase is 2-way (free).
//  blocks [4096, 4192): split W_off/W_attn -> Wc_hi/Wc_lo (96x256 hi/lo bf16)
//  blocks [4192, 4208): W_out (256x256 f32 k-major) -> Wt (256x256 f16 n-major)
// ---------------------------------------------------------------------------
__global__ __launch_bounds__(256) void kTP(const float* __restrict__ value,
                                           __half* __restrict__ val,
                                           const float* __restrict__ W_off,
                                           const float* __restrict__ W_attn,
                                           short* __restrict__ Wc_hi,
                                           short* __restrict__ Wc_lo,
                                           const float* __restrict__ Wsrc,
                                           __half* __restrict__ Wt) {
    __shared__ __align__(16) char smem[33280];
    const int t   = threadIdx.x;
    const int bid = blockIdx.x;

    if (bid < 4096) {
        float* tf = (float*)smem;                 // 32 x 260 f32 = 33280 B
        const int bh   = bid >> 6;
        const int pix0 = (bid & 63) * 256;
        const float* src = value + (size_t)bh * 32 * HW + pix0;
        // stage: one float4 (=4 pix) per row d; swizzled slot, b128 aligned
#pragma unroll
        for (int i = 0; i < 8; ++i) {
            int d = i * 4 + (t >> 6);
            int s = t & 63;
            float4 v = *(const float4*)&src[(size_t)d * HW + s * 4];
            int sx = s ^ ((d >> 3) << 2);
            *(float4*)&tf[d * 260 + sx * 4] = v;
        }
        __syncthreads();
        // read: 8 rows per (pix, d0-group), 2-way banks, cvt f16, 16B store
        const int u  = t >> 2;                    // 0..63
        const int a  = t & 3;                     // d-group
        const int d0 = a * 8;
#pragma unroll
        for (int j = 0; j < 4; ++j) {
            int pix = j * 64 + u;
            short o[8];
#pragma unroll
            for (int k = 0; k < 8; ++k) {
                int row = d0 + k;                 // row>>3 == a
                float f = tf[row * 260 +
                             (((pix >> 2) ^ (a << 2)) << 2) + (pix & 3)];
                __half hh = __float2half(f);
                o[k] = *reinterpret_cast<short*>(&hh);
            }
            *(bf16x8*)&val[((size_t)bh * HW + pix0 + pix) * 32 + d0] =
                *(bf16x8*)o;
        }
    } else if (bid < 4192) {
        const int c = bid - 4096;
        float v = (c < 64) ? W_off[(size_t)t * 64 + c]
                           : W_attn[(size_t)t * 32 + (c - 64)];
        short h = f2bf_s(v);
        short l = f2bf_s(v - bf_s2f(h));
        Wc_hi[(size_t)c * 256 + t] = h;
        Wc_lo[(size_t)c * 256 + t] = l;
    } else {
        float (*tile)[65] = (float (*)[65])smem;  // 64x65 f32 = 16640 B
        const int bx = bid - 4192;
        const int n0 = (bx & 3) * 64;
        const int k0 = (bx >> 2) * 64;
#pragma unroll
        for (int i = 0; i < 16; ++i) {
            int kk = i * 4 + (t >> 6);
            int nn = t & 63;
            tile[kk][nn] = Wsrc[(size_t)(k0 + kk) * 256 + n0 + nn];
        }
        __syncthreads();
#pragma unroll
        for (int i = 0; i < 16; ++i) {
            int nn = i * 4 + (t >> 6);
            int kk = t & 63;
            Wt[(size_t)(n0 + nn) * 256 + k0 + kk] = __float2half(tile[kk][nn]);
        }
    }
}

// ---------------------------------------------------------------------------
// kA1M: offset/attn GEMM via bf16 hi/lo MFMA (unchanged, verified)
// ---------------------------------------------------------------------------
__global__ __launch_bounds__(256) void kA1M(const float* __restrict__ query,
                                            const float* __restrict__ refp,
                                            const short* __restrict__ Wc_hi,
                                            const short* __restrict__ Wc_lo,
                                            const float* __restrict__ b_off,
                                            const float* __restrict__ b_attn,
                                            float4* __restrict__ locattn) {
    __shared__ __align__(16) char smem[57344];
    short* As_hi = (short*)smem;              // 128x64 bf16 = 16384 B
    short* As_lo = (short*)(smem + 16384);    // 16384 B
    short* Bs_hi = (short*)(smem + 32768);    // 96x64 bf16 = 12288 B
    short* Bs_lo = (short*)(smem + 45056);    // 12288 B
    float* Ct    = (float*)smem;              // 128x100 f32 = 51200 B (reuse)

    const int t    = threadIdx.x;
    const int lane = t & 63;
    const int w    = t >> 6;
    const int wm   = (w & 1) * 64;
    const int wn   = (w >> 1) * 48;
    const int quad = lane >> 4;
    const int l16  = lane & 15;
    const int row0 = blockIdx.x * 128;

    f32x4 acc[4][3];
#pragma unroll
    for (int mt = 0; mt < 4; ++mt)
#pragma unroll
        for (int nt = 0; nt < 3; ++nt)
            acc[mt][nt] = (f32x4){0.f, 0.f, 0.f, 0.f};

    for (int k0c = 0; k0c < 4; ++k0c) {
#pragma unroll
        for (int i = 0; i < 8; ++i) {
            int f   = t + i * 256;       // 0..2047 float4 index
            int row = f >> 4;
            int kq4 = f & 15;
            float4 q = *(const float4*)&query[(size_t)(row0 + row) * 256 +
                                              k0c * 64 + kq4 * 4];
            short4 hv, lv;
            hv.x = f2bf_s(q.x); lv.x = f2bf_s(q.x - bf_s2f(hv.x));
            hv.y = f2bf_s(q.y); lv.y = f2bf_s(q.y - bf_s2f(hv.y));
            hv.z = f2bf_s(q.z); lv.z = f2bf_s(q.z - bf_s2f(hv.z));
            hv.w = f2bf_s(q.w); lv.w = f2bf_s(q.w - bf_s2f(hv.w));
            int base = row * 64 + (((kq4 >> 1) ^ (row & 7)) * 8) + (kq4 & 1) * 4;
            *(short4*)&As_hi[base] = hv;
            *(short4*)&As_lo[base] = lv;
        }
#pragma unroll
        for (int i = 0; i < 3; ++i) {
            int idx = t + i * 256;       // 0..767 16B-block index
            int n   = idx >> 3;
            int kb  = idx & 7;
            int dst = n * 64 + ((kb ^ (n & 7)) * 8);
            *(uint4*)&Bs_hi[dst] =
                *(const uint4*)&Wc_hi[(size_t)n * 256 + k0c * 64 + kb * 8];
            *(uint4*)&Bs_lo[dst] =
                *(const uint4*)&Wc_lo[(size_t)n * 256 + k0c * 64 + kb * 8];
        }
        __syncthreads();

#pragma unroll
        for (int ks = 0; ks < 2; ++ks) {
            const int kq = ks * 4 + quad;
            bf16x8 ah[4], al[4], bh[3], bl[3];
#pragma unroll
            for (int mt = 0; mt < 4; ++mt) {
                int m = wm + mt * 16 + l16;
                ah[mt] = *(const bf16x8*)&As_hi[m * 64 + (kq ^ (m & 7)) * 8];
                al[mt] = *(const bf16x8*)&As_lo[m * 64 + (kq ^ (m & 7)) * 8];
            }
#pragma unroll
            for (int nt = 0; nt < 3; ++nt) {
                int n = wn + nt * 16 + l16;
                bh[nt] = *(const bf16x8*)&Bs_hi[n * 64 + (kq ^ (n & 7)) * 8];
                bl[nt] = *(const bf16x8*)&Bs_lo[n * 64 + (kq ^ (n & 7)) * 8];
            }
#pragma unroll
            for (int mt = 0; mt < 4; ++mt)
#pragma unroll
                for (int nt = 0; nt < 3; ++nt)
                    acc[mt][nt] = __builtin_amdgcn_mfma_f32_16x16x32_bf16(
                        ah[mt], bh[nt], acc[mt][nt], 0, 0, 0);
#pragma unroll
            for (int mt = 0; mt < 4; ++mt)
#pragma unroll
                for (int nt = 0; nt < 3; ++nt)
                    acc[mt][nt] = __builtin_amdgcn_mfma_f32_16x16x32_bf16(
                        ah[mt], bl[nt], acc[mt][nt], 0, 0, 0);
#pragma unroll
            for (int mt = 0; mt < 4; ++mt)
#pragma unroll
                for (int nt = 0; nt < 3; ++nt)
                    acc[mt][nt] = __builtin_amdgcn_mfma_f32_16x16x32_bf16(
                        al[mt], bh[nt], acc[mt][nt], 0, 0, 0);
        }
        __syncthreads();
    }

#pragma unroll
    for (int mt = 0; mt < 4; ++mt) {
#pragma unroll
        for (int nt = 0; nt < 3; ++nt) {
            int col = wn + nt * 16 + l16;
#pragma unroll
            for (int rI = 0; rI < 4; ++rI) {
                int row = wm + mt * 16 + quad * 4 + rI;
                Ct[row * 100 + col] = acc[mt][nt][rI];
            }
        }
    }
    __syncthreads();

    const int rg = t >> 3;
    const int h  = t & 7;
    float boff[8];
#pragma unroll
    for (int j = 0; j < 8; ++j) boff[j] = b_off[h * 8 + j];
    float batn[4];
#pragma unroll
    for (int j = 0; j < 4; ++j) batn[j] = b_attn[h * 4 + j];

#pragma unroll
    for (int r = 0; r < 4; ++r) {
        int row  = rg * 4 + r;
        int rowg = row0 + row;           // == b * N_ + n
        float rx = refp[(size_t)rowg * 2 + 0];
        float ry = refp[(size_t)rowg * 2 + 1];
        float4 lg4 = *(const float4*)&Ct[row * 100 + 64 + h * 4];
        float lg[4] = {lg4.x + batn[0], lg4.y + batn[1],
                       lg4.z + batn[2], lg4.w + batn[3]};
        float m = fmaxf(fmaxf(lg[0], lg[1]), fmaxf(lg[2], lg[3]));
        float e[4];
        float s = 0.f;
#pragma unroll
        for (int p = 0; p < 4; ++p) { e[p] = __expf(lg[p] - m); s += e[p]; }
        float inv = 1.f / s;
        float4 o0 = *(const float4*)&Ct[row * 100 + h * 8];
        float4 o1 = *(const float4*)&Ct[row * 100 + h * 8 + 4];
        float ox[4] = {o0.x + boff[0], o0.z + boff[2],
                       o1.x + boff[4], o1.z + boff[6]};
        float oy[4] = {o0.y + boff[1], o0.w + boff[3],
                       o1.y + boff[5], o1.w + boff[7]};
#pragma unroll
        for (int p = 0; p < 4; ++p) {
            float x = (rx * 2.f + ox[p]) * (W_ * 0.5f) - 0.5f;
            float y = (ry * 2.f + oy[p]) * (H_ * 0.5f) - 0.5f;
            locattn[(size_t)rowg * 32 + h * 4 + p] =
                make_float4(x, y, e[p] * inv, 0.f);
        }
    }
}

// ---------------------------------------------------------------------------
// kAC v2: fused sampling + out-GEMM (unchanged from round 6, verified 80 us)
// ---------------------------------------------------------------------------
__global__ __launch_bounds__(256, 4) void kAC(const float4* __restrict__ locattn,
                                              const __half* __restrict__ val,
                                              const __half* __restrict__ Wt,
                                              const float* __restrict__ bias,
                                              float* __restrict__ out) {
    __shared__ __align__(16) char smem[32768];
    char*  midc = smem;                       // 32 x 256 f16 swizzled, 16384 B
    uint4* ow   = (uint4*)(smem + 16384);     // 1024 records x 16 B
    short* Bs   = (short*)(smem + 16384);     // phase C alias: 256 x 32 f16

    const int t   = threadIdx.x;
    const int bid = blockIdx.x;
    const int b   = bid & 7;                  // XCD-aligned batch
    const int n0  = (bid >> 3) * 32;

    // ---- phase A: corner records (swizzled ow store) ----
#pragma unroll
    for (int i = 0; i < 4; ++i) {
        int item = t + i * 256;               // 0..1023
        int r  = item >> 5;
        int hp = item & 31;
        float4 L = locattn[((size_t)b * N_ + n0 + r) * 32 + hp];
        float x = L.x, y = L.y, a = L.z;
        float xf = floorf(x), yf = floorf(y);
        int x0 = (int)xf, y0 = (int)yf;
        int x1 = x0 + 1, y1 = y0 + 1;
        float wx1 = x - xf, wy1 = y - yf;
        float wx0 = 1.f - wx1, wy0 = 1.f - wy1;
        int cx0 = min(max(x0, 0), W_ - 1);
        int cx1 = min(max(x1, 0), W_ - 1);
        int cy0 = min(max(y0, 0), H_ - 1);
        int cy1 = min(max(y1, 0), H_ - 1);
        bool bx0 = (x0 >= 0) & (x0 < W_);
        bool bx1 = (x1 >= 0) & (x1 < W_);
        bool by0 = (y0 >= 0) & (y0 < H_);
        bool by1 = (y1 >= 0) & (y1 < H_);
        float f00 = a * wx0 * wy0 * ((bx0 & by0) ? 1.f : 0.f);
        float f10 = a * wx1 * wy0 * ((bx1 & by0) ? 1.f : 0.f);
        float f01 = a * wx0 * wy1 * ((bx0 & by1) ? 1.f : 0.f);
        float f11 = a * wx1 * wy1 * ((bx1 & by1) ? 1.f : 0.f);
        uint4 rec;
        rec.x = (unsigned)(cy0 * W_ + cx0) | ((unsigned)(cy0 * W_ + cx1) << 16);
        rec.y = (unsigned)(cy1 * W_ + cx0) | ((unsigned)(cy1 * W_ + cx1) << 16);
        __half2 wA = __floats2half2_rn(f00, f10);
        __half2 wB = __floats2half2_rn(f01, f11);
        rec.z = *reinterpret_cast<unsigned*>(&wA);
        rec.w = *reinterpret_cast<unsigned*>(&wB);
        ow[r * 32 + (hp ^ (r & 7))] = rec;    // swizzle kills bank-0 pileup
    }
    __syncthreads();

    // ---- phase B: gather + weighted sum -> midc ----
    {
        const int j8 = t & 7;                 // lane in 8-lane pixel group
        const int g  = t >> 3;                // 0..31 = row r
        const int d8 = j8 * 4;                // this lane's 4 d's
#pragma unroll
        for (int q = 0; q < 8; ++q) {         // q = head
            const char* vb = (const char*)val +
                (((size_t)b * 8 + q) * HW * 32 + d8) * 2;
            __half2 a01 = __float2half2_rn(0.f);
            __half2 a23 = __float2half2_rn(0.f);
#pragma unroll
            for (int p = 0; p < 4; ++p) {
                uint4 rec = ow[g * 32 + ((q * 4 + p) ^ (g & 7))];
                int i0 = rec.x & 0xffff, i1 = rec.x >> 16;
                int i2 = rec.y & 0xffff, i3 = rec.y >> 16;
                __half2 wA = *reinterpret_cast<__half2*>(&rec.z);
                __half2 wB = *reinterpret_cast<__half2*>(&rec.w);
                uint2 u0 = *(const uint2*)(vb + (size_t)i0 * 64);
                uint2 u1 = *(const uint2*)(vb + (size_t)i1 * 64);
                uint2 u2 = *(const uint2*)(vb + (size_t)i2 * 64);
                uint2 u3 = *(const uint2*)(vb + (size_t)i3 * 64);
                __half2 w00 = __low2half2(wA);
                a01 = __hfma2(*reinterpret_cast<__half2*>(&u0.x), w00, a01);
                a23 = __hfma2(*reinterpret_cast<__half2*>(&u0.y), w00, a23);
                __half2 w10 = __high2half2(wA);
                a01 = __hfma2(*reinterpret_cast<__half2*>(&u1.x), w10, a01);
                a23 = __hfma2(*reinterpret_cast<__half2*>(&u1.y), w10, a23);
                __half2 w01 = __low2half2(wB);
                a01 = __hfma2(*reinterpret_cast<__half2*>(&u2.x), w01, a01);
                a23 = __hfma2(*reinterpret_cast<__half2*>(&u2.y), w01, a23);
                __half2 w11 = __high2half2(wB);
                a01 = __hfma2(*reinterpret_cast<__half2*>(&u3.x), w11, a01);
                a23 = __hfma2(*reinterpret_cast<__half2*>(&u3.y), w11, a23);
            }
            int c8  = q * 4 + (j8 >> 1);      // 16B-unit along C (col/8)
            int off = g * 512 + ((c8 ^ (g & 7)) * 16) + (j8 & 1) * 8;
            uint2 st;
            st.x = *reinterpret_cast<unsigned*>(&a01);
            st.y = *reinterpret_cast<unsigned*>(&a23);
            *(uint2*)(midc + off) = st;
        }
    }
    __syncthreads();

    // ---- phase C: out = midc @ Wt^T + bias, BK=32, Bs from L2-hot Wt ----
    const int lane = t & 63;
    const int w    = t >> 6;
    const int wn   = w * 64;
    const int quad = lane >> 4;
    const int l16  = lane & 15;

    f32x4 acc[2][4];
#pragma unroll
    for (int mt = 0; mt < 2; ++mt)
#pragma unroll
        for (int nt = 0; nt < 4; ++nt)
            acc[mt][nt] = (f32x4){0.f, 0.f, 0.f, 0.f};

    for (int k0 = 0; k0 < 8; ++k0) {
        // stage Wt panel: 256 n x 32 k f16 = 16 KB (1024 uint4, 4/thread)
#pragma unroll
        for (int i = 0; i < 4; ++i) {
            int idx = t + i * 256;            // 0..1023
            int n   = idx >> 2;
            int kb  = idx & 3;
            *(uint4*)&Bs[n * 32 + ((kb ^ (n & 3)) * 8)] =
                *(const uint4*)&Wt[(size_t)n * 256 + k0 * 32 + kb * 8];
        }
        __syncthreads();

        f16x8 af[2], bfv[4];
#pragma unroll
        for (int mt = 0; mt < 2; ++mt) {
            int m = mt * 16 + l16;
            af[mt] = *(const f16x8*)(midc + m * 512 +
                                     (((k0 * 4 + quad) ^ (m & 7)) * 16));
        }
#pragma unroll
        for (int nt = 0; nt < 4; ++nt) {
            int n = wn + nt * 16 + l16;
            bfv[nt] = *(const f16x8*)&Bs[n * 32 + ((quad ^ (n & 3)) * 8)];
        }
#pragma unroll
        for (int mt = 0; mt < 2; ++mt)
#pragma unroll
            for (int nt = 0; nt < 4; ++nt)
                acc[mt][nt] = __builtin_amdgcn_mfma_f32_16x16x32_f16(
                    af[mt], bfv[nt], acc[mt][nt], 0, 0, 0);
        __syncthreads();
    }

    // ---- epilogue: stage 32x256 f32 tile in LDS, stream out as float4 ----
    float* ost = (float*)smem;                // 32 x 256 f32 = 32768 B
#pragma unroll
    for (int nt = 0; nt < 4; ++nt) {
        int col  = wn + nt * 16 + l16;
        float bv = bias[col];
#pragma unroll
        for (int mt = 0; mt < 2; ++mt) {
#pragma unroll
            for (int rI = 0; rI < 4; ++rI) {
                int row = mt * 16 + quad * 4 + rI;
                int byt = row * 1024 + ((col * 4) ^ ((row & 1) << 6));
                *(float*)((char*)ost + byt) = acc[mt][nt][rI] + bv;
            }
        }
    }
    __syncthreads();
#pragma unroll
    for (int i = 0; i < 8; ++i) {
        int idx = t + i * 256;                // 0..2047 float4 units
        int row = idx >> 6;
        int u   = idx & 63;
        float4 v = *(const float4*)((char*)ost +
                                    row * 1024 + ((u * 16) ^ ((row & 1) << 6)));
        *(float4*)&out[((size_t)b * N_ + n0 + row) * 256 + u * 4] = v;
    }
}

// ---------------------------------------------------------------------------
// launcher
// ws: val     [0,          67108864)  B*8*HW*32 f16
//     locattn [67108864,  100663296)  B*N*32 float4  (n-major)
//     Wt      [134217728, 134348800)  256*256 f16
//     Wc_hi   [134348800, 134397952)  96*256 bf16
//     Wc_lo   [134397952, 134447104)  96*256 bf16
// ---------------------------------------------------------------------------
extern "C" void kernel_launch(void* const* d_in, const int* in_sizes, int n_in,
                              void* d_out, int out_size, void* d_ws, size_t ws_size,
                              hipStream_t stream) {
    const float* query  = (const float*)d_in[0];
    const float* refp   = (const float*)d_in[1];
    const float* value  = (const float*)d_in[2];
    const float* W_off  = (const float*)d_in[3];
    const float* b_off  = (const float*)d_in[4];
    const float* W_attn = (const float*)d_in[5];
    const float* b_attn = (const float*)d_in[6];
    const float* W_out  = (const float*)d_in[7];
    const float* b_out  = (const float*)d_in[8];
    float* out = (float*)d_out;

    char*   ws      = (char*)d_ws;
    __half* val     = (__half*)(ws);
    float4* locattn = (float4*)(ws + 67108864);
    __half* Wt      = (__half*)(ws + 134217728);
    short*  Wc_hi   = (short*)(ws + 134348800);
    short*  Wc_lo   = (short*)(ws + 134397952);

    kTP <<<dim3(4208), 256, 0, stream>>>(value, val, W_off, W_attn,
                                         Wc_hi, Wc_lo, W_out, Wt);
    kA1M<<<dim3((B_ * N_) / 128), 256, 0, stream>>>(query, refp, Wc_hi, Wc_lo,
                                                    b_off, b_attn, locattn);
    kAC <<<dim3((B_ * N_) / 32), 256, 0, stream>>>(locattn, val, Wt,
                                                   b_out, out);
}

// Round 9
// 356.874 us; speedup vs baseline: 1.0199x; 1.0199x over previous
//
#include <hip/hip_runtime.h>
#include <hip/hip_bf16.h>
#include <hip/hip_fp16.h>
#include <cstddef>

#define B_  8
#define N_  8192
#define C_  256
#define H_  128
#define W_  128
#define HH  8
#define PP  4
#define DD  32
#define HW  (H_ * W_)

typedef short bf16x8 __attribute__((ext_vector_type(8)));
typedef _Float16 f16x8 __attribute__((ext_vector_type(8)));
typedef float f32x4  __attribute__((ext_vector_type(4)));

static __device__ __forceinline__ short f2bf_s(float f) {
    __hip_bfloat16 b = __float2bfloat16(f);
    return *reinterpret_cast<short*>(&b);
}
static __device__ __forceinline__ float bf_s2f(short s) {
    __hip_bfloat16 b = *reinterpret_cast<__hip_bfloat16*>(&s);
    return __bfloat162float(b);
}

// ---------------------------------------------------------------------------
// kP: small prep. blocks [0,96): W_off/W_attn -> Wc_hi/Wc_lo (96x256 hi/lo
// bf16, n-major). blocks [96,112): W_out -> Wt (256x256 f16 n-major).
// ---------------------------------------------------------------------------
__global__ __launch_bounds__(256) void kP(const float* __restrict__ W_off,
                                          const float* __restrict__ W_attn,
                                          short* __restrict__ Wc_hi,
                                          short* __restrict__ Wc_lo,
                                          const float* __restrict__ Wsrc,
                                          __half* __restrict__ Wt) {
    __shared__ float tile[64][65];
    const int t = threadIdx.x;
    if (blockIdx.x < 96) {
        const int c = blockIdx.x;
        float v = (c < 64) ? W_off[(size_t)t * 64 + c]
                           : W_attn[(size_t)t * 32 + (c - 64)];
        short h = f2bf_s(v);
        short l = f2bf_s(v - bf_s2f(h));
        Wc_hi[(size_t)c * 256 + t] = h;
        Wc_lo[(size_t)c * 256 + t] = l;
    } else {
        const int bx = blockIdx.x - 96;
        const int n0 = (bx & 3) * 64;
        const int k0 = (bx >> 2) * 64;
#pragma unroll
        for (int i = 0; i < 16; ++i) {
            int kk = i * 4 + (t >> 6);
            int nn = t & 63;
            tile[kk][nn] = Wsrc[(size_t)(k0 + kk) * 256 + n0 + nn];
        }
        __syncthreads();
#pragma unroll
        for (int i = 0; i < 16; ++i) {
            int nn = i * 4 + (t >> 6);
            int kk = t & 63;
            Wt[(size_t)(n0 + nn) * 256 + k0 + kk] = __float2half(tile[kk][nn]);
        }
    }
}

// ---------------------------------------------------------------------------
// kMain: merged offset/attn GEMM + value transpose (independent parts,
// co-resident for mem/VALU overlap + top-5 visibility).
//  blocks [0,512):    kA1M body  (row0 = bid*128)
//  blocks [512,4608): transpose value f32 -> val (B*8, HW, 32) f16
// ---------------------------------------------------------------------------
__global__ __launch_bounds__(256) void kMain(const float* __restrict__ query,
                                             const float* __restrict__ refp,
                                             const short* __restrict__ Wc_hi,
                                             const short* __restrict__ Wc_lo,
                                             const float* __restrict__ b_off,
                                             const float* __restrict__ b_attn,
                                             float4* __restrict__ locattn,
                                             const float* __restrict__ value,
                                             __half* __restrict__ val) {
    __shared__ __align__(16) char smem[57344];
    const int t   = threadIdx.x;
    const int bid = blockIdx.x;

    if (bid >= 512) {
        // ---- transpose part (stride-260 swizzled tile, verified r7) ----
        float* tf = (float*)smem;                 // 32 x 260 f32 = 33280 B
        const int tb   = bid - 512;
        const int bh   = tb >> 6;
        const int pix0 = (tb & 63) * 256;
        const float* src = value + (size_t)bh * 32 * HW + pix0;
#pragma unroll
        for (int i = 0; i < 8; ++i) {
            int d = i * 4 + (t >> 6);
            int s = t & 63;
            float4 v = *(const float4*)&src[(size_t)d * HW + s * 4];
            int sx = s ^ ((d >> 3) << 2);
            *(float4*)&tf[d * 260 + sx * 4] = v;
        }
        __syncthreads();
        const int u  = t >> 2;
        const int a  = t & 3;
        const int d0 = a * 8;
#pragma unroll
        for (int j = 0; j < 4; ++j) {
            int pix = j * 64 + u;
            short o[8];
#pragma unroll
            for (int k = 0; k < 8; ++k) {
                int row = d0 + k;
                float f = tf[row * 260 +
                             (((pix >> 2) ^ (a << 2)) << 2) + (pix & 3)];
                __half hh = __float2half(f);
                o[k] = *reinterpret_cast<short*>(&hh);
            }
            *(bf16x8*)&val[((size_t)bh * HW + pix0 + pix) * 32 + d0] =
                *(bf16x8*)o;
        }
        return;
    }

    // ---- kA1M part (unchanged body) ----
    short* As_hi = (short*)smem;              // 128x64 bf16 = 16384 B
    short* As_lo = (short*)(smem + 16384);    // 16384 B
    short* Bs_hi = (short*)(smem + 32768);    // 96x64 bf16 = 12288 B
    short* Bs_lo = (short*)(smem + 45056);    // 12288 B
    float* Ct    = (float*)smem;              // 128x100 f32 = 51200 B (reuse)

    const int lane = t & 63;
    const int w    = t >> 6;
    const int wm   = (w & 1) * 64;
    const int wn   = (w >> 1) * 48;
    const int quad = lane >> 4;
    const int l16  = lane & 15;
    const int row0 = bid * 128;

    f32x4 acc[4][3];
#pragma unroll
    for (int mt = 0; mt < 4; ++mt)
#pragma unroll
        for (int nt = 0; nt < 3; ++nt)
            acc[mt][nt] = (f32x4){0.f, 0.f, 0.f, 0.f};

    for (int k0c = 0; k0c < 4; ++k0c) {
#pragma unroll
        for (int i = 0; i < 8; ++i) {
            int f   = t + i * 256;       // 0..2047 float4 index
            int row = f >> 4;
            int kq4 = f & 15;
            float4 q = *(const float4*)&query[(size_t)(row0 + row) * 256 +
                                              k0c * 64 + kq4 * 4];
            short4 hv, lv;
            hv.x = f2bf_s(q.x); lv.x = f2bf_s(q.x - bf_s2f(hv.x));
            hv.y = f2bf_s(q.y); lv.y = f2bf_s(q.y - bf_s2f(hv.y));
            hv.z = f2bf_s(q.z); lv.z = f2bf_s(q.z - bf_s2f(hv.z));
            hv.w = f2bf_s(q.w); lv.w = f2bf_s(q.w - bf_s2f(hv.w));
            int base = row * 64 + (((kq4 >> 1) ^ (row & 7)) * 8) + (kq4 & 1) * 4;
            *(short4*)&As_hi[base] = hv;
            *(short4*)&As_lo[base] = lv;
        }
#pragma unroll
        for (int i = 0; i < 3; ++i) {
            int idx = t + i * 256;       // 0..767 16B-block index
            int n   = idx >> 3;
            int kb  = idx & 7;
            int dst = n * 64 + ((kb ^ (n & 7)) * 8);
            *(uint4*)&Bs_hi[dst] =
                *(const uint4*)&Wc_hi[(size_t)n * 256 + k0c * 64 + kb * 8];
            *(uint4*)&Bs_lo[dst] =
                *(const uint4*)&Wc_lo[(size_t)n * 256 + k0c * 64 + kb * 8];
        }
        __syncthreads();

#pragma unroll
        for (int ks = 0; ks < 2; ++ks) {
            const int kq = ks * 4 + quad;
            bf16x8 ah[4], al[4], bh[3], bl[3];
#pragma unroll
            for (int mt = 0; mt < 4; ++mt) {
                int m = wm + mt * 16 + l16;
                ah[mt] = *(const bf16x8*)&As_hi[m * 64 + (kq ^ (m & 7)) * 8];
                al[mt] = *(const bf16x8*)&As_lo[m * 64 + (kq ^ (m & 7)) * 8];
            }
#pragma unroll
            for (int nt = 0; nt < 3; ++nt) {
                int n = wn + nt * 16 + l16;
                bh[nt] = *(const bf16x8*)&Bs_hi[n * 64 + (kq ^ (n & 7)) * 8];
                bl[nt] = *(const bf16x8*)&Bs_lo[n * 64 + (kq ^ (n & 7)) * 8];
            }
#pragma unroll
            for (int mt = 0; mt < 4; ++mt)
#pragma unroll
                for (int nt = 0; nt < 3; ++nt)
                    acc[mt][nt] = __builtin_amdgcn_mfma_f32_16x16x32_bf16(
                        ah[mt], bh[nt], acc[mt][nt], 0, 0, 0);
#pragma unroll
            for (int mt = 0; mt < 4; ++mt)
#pragma unroll
                for (int nt = 0; nt < 3; ++nt)
                    acc[mt][nt] = __builtin_amdgcn_mfma_f32_16x16x32_bf16(
                        ah[mt], bl[nt], acc[mt][nt], 0, 0, 0);
#pragma unroll
            for (int mt = 0; mt < 4; ++mt)
#pragma unroll
                for (int nt = 0; nt < 3; ++nt)
                    acc[mt][nt] = __builtin_amdgcn_mfma_f32_16x16x32_bf16(
                        al[mt], bh[nt], acc[mt][nt], 0, 0, 0);
        }
        __syncthreads();
    }

#pragma unroll
    for (int mt = 0; mt < 4; ++mt) {
#pragma unroll
        for (int nt = 0; nt < 3; ++nt) {
            int col = wn + nt * 16 + l16;
#pragma unroll
            for (int rI = 0; rI < 4; ++rI) {
                int row = wm + mt * 16 + quad * 4 + rI;
                Ct[row * 100 + col] = acc[mt][nt][rI];
            }
        }
    }
    __syncthreads();

    const int rg = t >> 3;
    const int h  = t & 7;
    float boff[8];
#pragma unroll
    for (int j = 0; j < 8; ++j) boff[j] = b_off[h * 8 + j];
    float batn[4];
#pragma unroll
    for (int j = 0; j < 4; ++j) batn[j] = b_attn[h * 4 + j];

#pragma unroll
    for (int r = 0; r < 4; ++r) {
        int row  = rg * 4 + r;
        int rowg = row0 + row;           // == b * N_ + n
        float rx = refp[(size_t)rowg * 2 + 0];
        float ry = refp[(size_t)rowg * 2 + 1];
        float4 lg4 = *(const float4*)&Ct[row * 100 + 64 + h * 4];
        float lg[4] = {lg4.x + batn[0], lg4.y + batn[1],
                       lg4.z + batn[2], lg4.w + batn[3]};
        float m = fmaxf(fmaxf(lg[0], lg[1]), fmaxf(lg[2], lg[3]));
        float e[4];
        float s = 0.f;
#pragma unroll
        for (int p = 0; p < 4; ++p) { e[p] = __expf(lg[p] - m); s += e[p]; }
        float inv = 1.f / s;
        float4 o0 = *(const float4*)&Ct[row * 100 + h * 8];
        float4 o1 = *(const float4*)&Ct[row * 100 + h * 8 + 4];
        float ox[4] = {o0.x + boff[0], o0.z + boff[2],
                       o1.x + boff[4], o1.z + boff[6]};
        float oy[4] = {o0.y + boff[1], o0.w + boff[3],
                       o1.y + boff[5], o1.w + boff[7]};
#pragma unroll
        for (int p = 0; p < 4; ++p) {
            float x = (rx * 2.f + ox[p]) * (W_ * 0.5f) - 0.5f;
            float y = (ry * 2.f + oy[p]) * (H_ * 0.5f) - 0.5f;
            locattn[(size_t)rowg * 32 + h * 4 + p] =
                make_float4(x, y, e[p] * inv, 0.f);
        }
    }
}

// ---------------------------------------------------------------------------
// kAC v2: fused sampling + out-GEMM. 32 KB LDS; min-waves 5 -> 5 blocks/CU
// (5 x 32768 = 163840 B = full LDS pool), was 4.
// ---------------------------------------------------------------------------
__global__ __launch_bounds__(256, 5) void kAC(const float4* __restrict__ locattn,
                                              const __half* __restrict__ val,
                                              const __half* __restrict__ Wt,
                                              const float* __restrict__ bias,
                                              float* __restrict__ out) {
    __shared__ __align__(16) char smem[32768];
    char*  midc = smem;                       // 32 x 256 f16 swizzled, 16384 B
    uint4* ow   = (uint4*)(smem + 16384);     // 1024 records x 16 B
    short* Bs   = (short*)(smem + 16384);     // phase C alias: 256 x 32 f16

    const int t   = threadIdx.x;
    const int bid = blockIdx.x;
    const int b   = bid & 7;                  // XCD-aligned batch
    const int n0  = (bid >> 3) * 32;

    // ---- phase A: corner records (swizzled ow store) ----
#pragma unroll
    for (int i = 0; i < 4; ++i) {
        int item = t + i * 256;               // 0..1023
        int r  = item >> 5;
        int hp = item & 31;
        float4 L = locattn[((size_t)b * N_ + n0 + r) * 32 + hp];
        float x = L.x, y = L.y, a = L.z;
        float xf = floorf(x), yf = floorf(y);
        int x0 = (int)xf, y0 = (int)yf;
        int x1 = x0 + 1, y1 = y0 + 1;
        float wx1 = x - xf, wy1 = y - yf;
        float wx0 = 1.f - wx1, wy0 = 1.f - wy1;
        int cx0 = min(max(x0, 0), W_ - 1);
        int cx1 = min(max(x1, 0), W_ - 1);
        int cy0 = min(max(y0, 0), H_ - 1);
        int cy1 = min(max(y1, 0), H_ - 1);
        bool bx0 = (x0 >= 0) & (x0 < W_);
        bool bx1 = (x1 >= 0) & (x1 < W_);
        bool by0 = (y0 >= 0) & (y0 < H_);
        bool by1 = (y1 >= 0) & (y1 < H_);
        float f00 = a * wx0 * wy0 * ((bx0 & by0) ? 1.f : 0.f);
        float f10 = a * wx1 * wy0 * ((bx1 & by0) ? 1.f : 0.f);
        float f01 = a * wx0 * wy1 * ((bx0 & by1) ? 1.f : 0.f);
        float f11 = a * wx1 * wy1 * ((bx1 & by1) ? 1.f : 0.f);
        uint4 rec;
        rec.x = (unsigned)(cy0 * W_ + cx0) | ((unsigned)(cy0 * W_ + cx1) << 16);
        rec.y = (unsigned)(cy1 * W_ + cx0) | ((unsigned)(cy1 * W_ + cx1) << 16);
        __half2 wA = __floats2half2_rn(f00, f10);
        __half2 wB = __floats2half2_rn(f01, f11);
        rec.z = *reinterpret_cast<unsigned*>(&wA);
        rec.w = *reinterpret_cast<unsigned*>(&wB);
        ow[r * 32 + (hp ^ (r & 7))] = rec;    // swizzle kills bank-0 pileup
    }
    __syncthreads();

    // ---- phase B: gather + weighted sum -> midc ----
    {
        const int j8 = t & 7;                 // lane in 8-lane pixel group
        const int g  = t >> 3;                // 0..31 = row r
        const int d8 = j8 * 4;                // this lane's 4 d's
#pragma unroll
        for (int q = 0; q < 8; ++q) {         // q = head
            const char* vb = (const char*)val +
                (((size_t)b * 8 + q) * HW * 32 + d8) * 2;
            __half2 a01 = __float2half2_rn(0.f);
            __half2 a23 = __float2half2_rn(0.f);
#pragma unroll
            for (int p = 0; p < 4; ++p) {
                uint4 rec = ow[g * 32 + ((q * 4 + p) ^ (g & 7))];
                int i0 = rec.x & 0xffff, i1 = rec.x >> 16;
                int i2 = rec.y & 0xffff, i3 = rec.y >> 16;
                __half2 wA = *reinterpret_cast<__half2*>(&rec.z);
                __half2 wB = *reinterpret_cast<__half2*>(&rec.w);
                uint2 u0 = *(const uint2*)(vb + (size_t)i0 * 64);
                uint2 u1 = *(const uint2*)(vb + (size_t)i1 * 64);
                uint2 u2 = *(const uint2*)(vb + (size_t)i2 * 64);
                uint2 u3 = *(const uint2*)(vb + (size_t)i3 * 64);
                __half2 w00 = __low2half2(wA);
                a01 = __hfma2(*reinterpret_cast<__half2*>(&u0.x), w00, a01);
                a23 = __hfma2(*reinterpret_cast<__half2*>(&u0.y), w00, a23);
                __half2 w10 = __high2half2(wA);
                a01 = __hfma2(*reinterpret_cast<__half2*>(&u1.x), w10, a01);
                a23 = __hfma2(*reinterpret_cast<__half2*>(&u1.y), w10, a23);
                __half2 w01 = __low2half2(wB);
                a01 = __hfma2(*reinterpret_cast<__half2*>(&u2.x), w01, a01);
                a23 = __hfma2(*reinterpret_cast<__half2*>(&u2.y), w01, a23);
                __half2 w11 = __high2half2(wB);
                a01 = __hfma2(*reinterpret_cast<__half2*>(&u3.x), w11, a01);
                a23 = __hfma2(*reinterpret_cast<__half2*>(&u3.y), w11, a23);
            }
            int c8  = q * 4 + (j8 >> 1);      // 16B-unit along C (col/8)
            int off = g * 512 + ((c8 ^ (g & 7)) * 16) + (j8 & 1) * 8;
            uint2 st;
            st.x = *reinterpret_cast<unsigned*>(&a01);
            st.y = *reinterpret_cast<unsigned*>(&a23);
            *(uint2*)(midc + off) = st;
        }
    }
    __syncthreads();

    // ---- phase C: out = midc @ Wt^T + bias, BK=32, Bs from L2-hot Wt ----
    const int lane = t & 63;
    const int w    = t >> 6;
    const int wn   = w * 64;
    const int quad = lane >> 4;
    const int l16  = lane & 15;

    f32x4 acc[2][4];
#pragma unroll
    for (int mt = 0; mt < 2; ++mt)
#pragma unroll
        for (int nt = 0; nt < 4; ++nt)
            acc[mt][nt] = (f32x4){0.f, 0.f, 0.f, 0.f};

    for (int k0 = 0; k0 < 8; ++k0) {
        // stage Wt panel: 256 n x 32 k f16 = 16 KB (1024 uint4, 4/thread)
#pragma unroll
        for (int i = 0; i < 4; ++i) {
            int idx = t + i * 256;            // 0..1023
            int n   = idx >> 2;
            int kb  = idx & 3;
            *(uint4*)&Bs[n * 32 + ((kb ^ (n & 3)) * 8)] =
                *(const uint4*)&Wt[(size_t)n * 256 + k0 * 32 + kb * 8];
        }
        __syncthreads();

        f16x8 af[2], bfv[4];
#pragma unroll
        for (int mt = 0; mt < 2; ++mt) {
            int m = mt * 16 + l16;
            af[mt] = *(const f16x8*)(midc + m * 512 +
                                     (((k0 * 4 + quad) ^ (m & 7)) * 16));
        }
#pragma unroll
        for (int nt = 0; nt < 4; ++nt) {
            int n = wn + nt * 16 + l16;
            bfv[nt] = *(const f16x8*)&Bs[n * 32 + ((quad ^ (n & 3)) * 8)];
        }
#pragma unroll
        for (int mt = 0; mt < 2; ++mt)
#pragma unroll
            for (int nt = 0; nt < 4; ++nt)
                acc[mt][nt] = __builtin_amdgcn_mfma_f32_16x16x32_f16(
                    af[mt], bfv[nt], acc[mt][nt], 0, 0, 0);
        __syncthreads();
    }

    // ---- epilogue: stage 32x256 f32 tile in LDS, stream out as float4 ----
    float* ost = (float*)smem;                // 32 x 256 f32 = 32768 B
#pragma unroll
    for (int nt = 0; nt < 4; ++nt) {
        int col  = wn + nt * 16 + l16;
        float bv = bias[col];
#pragma unroll
        for (int mt = 0; mt < 2; ++mt) {
#pragma unroll
            for (int rI = 0; rI < 4; ++rI) {
                int row = mt * 16 + quad * 4 + rI;
                int byt = row * 1024 + ((col * 4) ^ ((row & 1) << 6));
                *(float*)((char*)ost + byt) = acc[mt][nt][rI] + bv;
            }
        }
    }
    __syncthreads();
#pragma unroll
    for (int i = 0; i < 8; ++i) {
        int idx = t + i * 256;                // 0..2047 float4 units
        int row = idx >> 6;
        int u   = idx & 63;
        float4 v = *(const float4*)((char*)ost +
                                    row * 1024 + ((u * 16) ^ ((row & 1) << 6)));
        *(float4*)&out[((size_t)b * N_ + n0 + row) * 256 + u * 4] = v;
    }
}

// ---------------------------------------------------------------------------
// launcher
// ws: val     [0,          67108864)  B*8*HW*32 f16
//     locattn [67108864,  100663296)  B*N*32 float4  (n-major)
//     Wt      [134217728, 134348800)  256*256 f16
//     Wc_hi   [134348800, 134397952)  96*256 bf16
//     Wc_lo   [134397952, 134447104)  96*256 bf16
// ---------------------------------------------------------------------------
extern "C" void kernel_launch(void* const* d_in, const int* in_sizes, int n_in,
                              void* d_out, int out_size, void* d_ws, size_t ws_size,
                              hipStream_t stream) {
    const float* query  = (const float*)d_in[0];
    const float* refp   = (const float*)d_in[1];
    const float* value  = (const float*)d_in[2];
    const float* W_off  = (const float*)d_in[3];
    const float* b_off  = (const float*)d_in[4];
    const float* W_attn = (const float*)d_in[5];
    const float* b_attn = (const float*)d_in[6];
    const float* W_out  = (const float*)d_in[7];
    const float* b_out  = (const float*)d_in[8];
    float* out = (float*)d_out;

    char*   ws      = (char*)d_ws;
    __half* val     = (__half*)(ws);
    float4* locattn = (float4*)(ws + 67108864);
    __half* Wt      = (__half*)(ws + 134217728);
    short*  Wc_hi   = (short*)(ws + 134348800);
    short*  Wc_lo   = (short*)(ws + 134397952);

    kP   <<<dim3(112), 256, 0, stream>>>(W_off, W_attn, Wc_hi, Wc_lo,
                                         W_out, Wt);
    kMain<<<dim3(4608), 256, 0, stream>>>(query, refp, Wc_hi, Wc_lo,
                                          b_off, b_attn, locattn, value, val);
    kAC  <<<dim3((B_ * N_) / 32), 256, 0, stream>>>(locattn, val, Wt,
                                                    b_out, out);
}